// Round 1
// 426.626 us; speedup vs baseline: 1.0766x; 1.0766x over previous
//
#include <hip/hip_runtime.h>
#include <math.h>

#define N_NODES 100000
#define N_EDGES 1600000
#define IN_F    128
#define NH1     8
#define HID     8
#define C1      64   // NH1*HID
#define C2      40   // N_CLASSES
#define SCAN_B  256
#define N_SBLK  ((N_NODES + SCAN_B - 1) / SCAN_B)   // 391

typedef unsigned short ushort_t;
typedef unsigned int uint_t;
typedef _Float16 half_t;
typedef short short8 __attribute__((ext_vector_type(8)));
typedef float f32x4 __attribute__((ext_vector_type(4)));

__device__ __forceinline__ float lrelu(float x) { return x > 0.f ? x : 0.2f * x; }
__device__ __forceinline__ ushort_t f2bf(float f) {
    uint_t u = __float_as_uint(f);
    u = (u + 0x7FFFu + ((u >> 16) & 1u)) >> 16;   // round-to-nearest-even
    return (ushort_t)u;
}
__device__ __forceinline__ float bf2f(ushort_t s) {
    return __uint_as_float(((uint_t)s) << 16);
}

// ---- x -> bf16 cast (streaming, 8 elems/thread) ----
__global__ __launch_bounds__(256) void k_xcast(
    const float* __restrict__ x, ushort_t* __restrict__ xb)
{
    size_t i8 = (size_t)(blockIdx.x * 256 + threadIdx.x) * 8;   // 12.8M total
    float4 a = *(const float4*)(x + i8);
    float4 b = *(const float4*)(x + i8 + 4);
    ushort_t o[8] = {f2bf(a.x), f2bf(a.y), f2bf(a.z), f2bf(a.w),
                     f2bf(b.x), f2bf(b.y), f2bf(b.z), f2bf(b.w)};
    *(int4*)(xb + i8) = *(const int4*)o;
}

// ---- W1 pre-swizzle: B-frags for mfma_f32_16x16x32_bf16.
//      W1p[((s*4+nt)*64+lane)*8+j] = W1[k=s*32+(lane>>4)*8+j][n=nt*16+(lane&15)] ----
__global__ __launch_bounds__(256) void k_w1prep(
    const float* __restrict__ W1, ushort_t* __restrict__ W1p)
{
    int i = blockIdx.x * 256 + threadIdx.x;     // 8192
    if (i >= 8192) return;
    int j = i & 7, lane = (i >> 3) & 63, nt = (i >> 9) & 3, s = i >> 11;
    int k = s * 32 + (lane >> 4) * 8 + j;
    int n = nt * 16 + (lane & 15);
    W1p[i] = f2bf(W1[k * C1 + n]);
}

// ---- GEMM1 (MFMA): H1[100k x 64] = xb[100k x 128] @ W1. Wave per
//      16-node tile: 4 K-steps x 4 N-tiles = 16 MFMAs. ----
__global__ __launch_bounds__(256) void k_gemm1_mfma(
    const ushort_t* __restrict__ xb, const ushort_t* __restrict__ W1p,
    ushort_t* __restrict__ H1)
{
    int tile = (blockIdx.x * blockDim.x + threadIdx.x) >> 6;
    int lane = threadIdx.x & 63;
    if (tile >= N_NODES / 16) return;
    int quad = lane >> 4, lo = lane & 15;
    const ushort_t* arow = xb + ((size_t)tile * 16 + lo) * IN_F + quad * 8;
    short8 a0 = *(const short8*)arow;            // k = 0*32 + quad*8+j
    short8 a1 = *(const short8*)(arow + 32);
    short8 a2 = *(const short8*)(arow + 64);
    short8 a3 = *(const short8*)(arow + 96);
    f32x4 acc[4] = {{0,0,0,0},{0,0,0,0},{0,0,0,0},{0,0,0,0}};
    #pragma unroll
    for (int nt = 0; nt < 4; ++nt) {
        short8 b0 = *(const short8*)&W1p[((0 * 4 + nt) * 64 + lane) * 8];
        short8 b1 = *(const short8*)&W1p[((1 * 4 + nt) * 64 + lane) * 8];
        short8 b2 = *(const short8*)&W1p[((2 * 4 + nt) * 64 + lane) * 8];
        short8 b3 = *(const short8*)&W1p[((3 * 4 + nt) * 64 + lane) * 8];
        acc[nt] = __builtin_amdgcn_mfma_f32_16x16x32_bf16(a0, b0, acc[nt], 0, 0, 0);
        acc[nt] = __builtin_amdgcn_mfma_f32_16x16x32_bf16(a1, b1, acc[nt], 0, 0, 0);
        acc[nt] = __builtin_amdgcn_mfma_f32_16x16x32_bf16(a2, b2, acc[nt], 0, 0, 0);
        acc[nt] = __builtin_amdgcn_mfma_f32_16x16x32_bf16(a3, b3, acc[nt], 0, 0, 0);
    }
    int nb = tile * 16 + quad * 4;               // C/D: col=lo, row=quad*4+reg
    #pragma unroll
    for (int nt = 0; nt < 4; ++nt) {
        int cb = nt * 16 + lo;
        #pragma unroll
        for (int r = 0; r < 4; ++r)
            H1[(size_t)(nb + r) * C1 + cb] = f2bf(acc[nt][r]);
    }
}

// ---- s1/d1 dots from H1: wave per node, lane = h*8+f ----
__global__ __launch_bounds__(256) void k_sd1(
    const ushort_t* __restrict__ H1,
    const float* __restrict__ as1, const float* __restrict__ ad1,
    float* __restrict__ s1, float* __restrict__ d1)
{
    int n = (blockIdx.x * blockDim.x + threadIdx.x) >> 6;
    int lane = threadIdx.x & 63;
    if (n >= N_NODES) return;
    float h = bf2f(H1[(size_t)n * C1 + lane]);
    float ps = h * as1[lane], pd = h * ad1[lane];
    #pragma unroll
    for (int off = 4; off; off >>= 1) {
        ps += __shfl_xor(ps, off);
        pd += __shfl_xor(pd, off);
    }
    if ((lane & 7) == 0) {
        s1[n * NH1 + (lane >> 3)] = ps;
        d1[n * NH1 + (lane >> 3)] = pd;
    }
}

// ---- W2 pre-swizzle (as R9, verified) ----
__global__ __launch_bounds__(256) void k_w2prep(
    const float* __restrict__ W2, ushort_t* __restrict__ W2p)
{
    int i = blockIdx.x * 256 + threadIdx.x;
    if (i >= 3072) return;
    int j = i & 7, lane = (i >> 3) & 63, khalf = (i >> 9) & 1, nt = i >> 10;
    int n = nt * 16 + (lane & 15);
    int k = khalf * 32 + (lane >> 4) * 8 + j;
    float v = (n < C2) ? W2[k * C2 + n] : 0.f;
    W2p[i] = f2bf(v);
}

// ---- CSR build: degree count + per-edge rank ----
__global__ __launch_bounds__(256) void k_count(
    const int* __restrict__ ei, int* __restrict__ deg, int* __restrict__ rank)
{
    int e = blockIdx.x * blockDim.x + threadIdx.x;
    if (e >= N_EDGES) return;
    rank[e] = atomicAdd(&deg[ei[N_EDGES + e]], 1);
}

// ---- scan phase 1 ----
__global__ __launch_bounds__(SCAN_B) void k_red(
    const int* __restrict__ deg, int* __restrict__ bsum)
{
    int t = threadIdx.x, lane = t & 63, wv = t >> 6;
    int i = blockIdx.x * SCAN_B + t;
    int v = (i < N_NODES) ? deg[i] : 0;
    #pragma unroll
    for (int off = 32; off; off >>= 1) v += __shfl_xor(v, off);
    __shared__ int s[4];
    if (lane == 0) s[wv] = v;
    __syncthreads();
    if (t == 0) bsum[blockIdx.x] = s[0] + s[1] + s[2] + s[3];
}

// ---- scan phase 2 ----
__global__ __launch_bounds__(512) void k_scan_small(
    const int* __restrict__ bsum, int* __restrict__ boff,
    int* __restrict__ rowptr)
{
    __shared__ int s[512];
    int t = threadIdx.x;
    int v = (t < N_SBLK) ? bsum[t] : 0;
    s[t] = v;
    __syncthreads();
    for (int off = 1; off < 512; off <<= 1) {
        int u = (t >= off) ? s[t - off] : 0;
        __syncthreads();
        s[t] += u;
        __syncthreads();
    }
    if (t < N_SBLK) boff[t] = s[t] - v;
    if (t == 511) rowptr[N_NODES] = s[511];
}

// ---- scan phase 3 ----
__global__ __launch_bounds__(SCAN_B) void k_apply(
    const int* __restrict__ deg, const int* __restrict__ boff,
    int* __restrict__ rowptr)
{
    int t = threadIdx.x, lane = t & 63, wv = t >> 6;
    int i = blockIdx.x * SCAN_B + t;
    int v = (i < N_NODES) ? deg[i] : 0;
    int inc = v;
    #pragma unroll
    for (int off = 1; off < 64; off <<= 1) {
        int u = __shfl_up(inc, off);
        if (lane >= off) inc += u;
    }
    __shared__ int ws_[4];
    if (lane == 63) ws_[wv] = inc;
    __syncthreads();
    int add = 0;
    for (int k = 0; k < wv; k++) add += ws_[k];
    if (i < N_NODES) rowptr[i] = inc - v + add + boff[blockIdx.x];
}

// ---- CSR fill: no atomics, one 8-B store/edge ----
__global__ __launch_bounds__(256) void k_fill(
    const int* __restrict__ ei, const float* __restrict__ ea,
    const int* __restrict__ rowptr, const int* __restrict__ rank,
    int2* __restrict__ edges)
{
    int e = blockIdx.x * blockDim.x + threadIdx.x;
    if (e >= N_EDGES) return;
    int s = ei[e], d = ei[N_EDGES + e];
    int pos = rowptr[d] + rank[e];
    edges[pos] = make_int2(s, __float_as_int(ea[e]));
}

// ---- K_logit1: p1 AoS [E][8] fp16. 1-stage SW pipeline on edges load ----
__global__ __launch_bounds__(256) void k_logit1(
    const int* __restrict__ rowptr, const int2* __restrict__ edges,
    const float* __restrict__ s1, const float* __restrict__ d1,
    const float* __restrict__ ae1, half_t* __restrict__ p1)
{
    int w = (blockIdx.x * blockDim.x + threadIdx.x) >> 6;
    int lane = threadIdx.x & 63;
    if (w >= N_NODES) return;
    int hL = lane & 7, eL = lane >> 3;
    int jb = rowptr[w], je = rowptr[w + 1];
    if (jb >= je) return;
    float d1L = d1[w * NH1 + hL];
    float aeL = ae1[hL];
    int idx = jb + eL;
    int2 ed = edges[idx < je ? idx : jb];
    for (int base = jb; base < je; base += 8) {
        int nidx = idx + 8;
        int2 ned = edges[nidx < je ? nidx : jb];   // prefetch next group
        bool valid = idx < je;
        float l = lrelu(s1[ed.x * NH1 + hL] + d1L + __int_as_float(ed.y) * aeL);
        if (valid) p1[(size_t)idx * NH1 + hL] = (half_t)__expf(l);
        ed = ned; idx = nidx;
    }
}

// ---- K_node1: LDS-staged edge list -> independent gathers.
//      One coalesced lane-parallel load pulls 64 edges' (src) + 8 p-halves;
//      inner loop reads them via broadcast ds_read so only the H1 gather
//      is on the memory critical path. ----
__global__ __launch_bounds__(256) void k_node1(
    const int* __restrict__ rowptr, const int2* __restrict__ edges,
    const half_t* __restrict__ p1, const ushort_t* __restrict__ H1,
    ushort_t* __restrict__ out1r)
{
    __shared__ int    sm_s[4][64];
    __shared__ half_t sm_p[4][64 * 8];    // [e*8 + h]
    int w = (blockIdx.x * blockDim.x + threadIdx.x) >> 6;
    int lane = threadIdx.x & 63;
    int wv = (threadIdx.x >> 6) & 3;
    if (w >= N_NODES) return;
    int hA = lane >> 3;
    int jb = rowptr[w], je = rowptr[w + 1];
    float den0 = 0.f, den1 = 0.f;
    float acc0 = 0.f, acc1 = 0.f;
    const ushort_t* H1c = H1 + lane;
    const half_t* pp = &sm_p[wv][hA];
    for (int base = jb; base < je; base += 64) {
        int idx = base + lane;
        int s = 0;
        int4 pv = make_int4(0, 0, 0, 0);
        if (idx < je) {
            s = edges[idx].x;
            pv = *(const int4*)(p1 + (size_t)idx * NH1);   // 8 halves of this edge
        }
        sm_s[wv][lane] = s;
        *(int4*)&sm_p[wv][lane * 8] = pv;
        __builtin_amdgcn_wave_barrier();
        int cnt = min(64, je - base);
        int cnt4 = (cnt + 3) & ~3;          // pad edges have p=0 -> contribute 0
        for (int e = 0; e < cnt4; e += 4) {
            int s0  = sm_s[wv][e + 0];
            int s1_ = sm_s[wv][e + 1];
            int s2_ = sm_s[wv][e + 2];
            int s3  = sm_s[wv][e + 3];
            float p0  = (float)pp[(e + 0) * 8];
            float p1v = (float)pp[(e + 1) * 8];
            float p2v = (float)pp[(e + 2) * 8];
            float p3  = (float)pp[(e + 3) * 8];
            float h0  = bf2f(H1c[(size_t)s0  * C1]);
            float h1  = bf2f(H1c[(size_t)s1_ * C1]);
            float h2_ = bf2f(H1c[(size_t)s2_ * C1]);
            float h3  = bf2f(H1c[(size_t)s3  * C1]);
            den0 += p0 + p1v;
            den1 += p2v + p3;
            acc0 = fmaf(p0,  h0,  fmaf(p1v, h1, acc0));
            acc1 = fmaf(p2v, h2_, fmaf(p3,  h3, acc1));
        }
        __builtin_amdgcn_wave_barrier();
    }
    float den = den0 + den1;
    float acc = acc0 + acc1;
    float o = acc / (den + 1e-16f);
    float r = o > 0.f ? o : __expf(o) - 1.f;   // elu
    out1r[(size_t)w * C1 + lane] = f2bf(r);
}

// ---- K_gemm2 (MFMA, verified R9): H2 = out1r @ W2 + s2/d2 dots ----
__global__ __launch_bounds__(256) void k_gemm2(
    const ushort_t* __restrict__ out1r, const ushort_t* __restrict__ W2p,
    const float* __restrict__ as2, const float* __restrict__ ad2,
    ushort_t* __restrict__ H2, float* __restrict__ s2, float* __restrict__ d2)
{
    int tile = (blockIdx.x * blockDim.x + threadIdx.x) >> 6;
    int lane = threadIdx.x & 63;
    if (tile >= N_NODES / 16) return;
    int quad = lane >> 4, lo = lane & 15;
    const ushort_t* arow = out1r + ((size_t)tile * 16 + lo) * C1 + quad * 8;
    short8 a0 = *(const short8*)arow;
    short8 a1 = *(const short8*)(arow + 32);
    f32x4 acc[3] = {{0,0,0,0},{0,0,0,0},{0,0,0,0}};
    #pragma unroll
    for (int nt = 0; nt < 3; ++nt) {
        short8 b0 = *(const short8*)&W2p[((nt * 2 + 0) * 64 + lane) * 8];
        short8 b1 = *(const short8*)&W2p[((nt * 2 + 1) * 64 + lane) * 8];
        acc[nt] = __builtin_amdgcn_mfma_f32_16x16x32_bf16(a0, b0, acc[nt], 0, 0, 0);
        acc[nt] = __builtin_amdgcn_mfma_f32_16x16x32_bf16(a1, b1, acc[nt], 0, 0, 0);
    }
    float ps0 = 0.f, ps1 = 0.f, ps2 = 0.f, ps3 = 0.f;
    float pd0 = 0.f, pd1 = 0.f, pd2 = 0.f, pd3 = 0.f;
    #pragma unroll
    for (int nt = 0; nt < 3; ++nt) {
        int cb = nt * 16 + lo;
        float a2 = cb < C2 ? as2[cb] : 0.f;
        float b2 = cb < C2 ? ad2[cb] : 0.f;
        float v0 = acc[nt][0], v1 = acc[nt][1], v2 = acc[nt][2], v3 = acc[nt][3];
        int nb = tile * 16 + quad * 4;
        H2[(size_t)(nb + 0) * C1 + cb] = f2bf(v0);
        H2[(size_t)(nb + 1) * C1 + cb] = f2bf(v1);
        H2[(size_t)(nb + 2) * C1 + cb] = f2bf(v2);
        H2[(size_t)(nb + 3) * C1 + cb] = f2bf(v3);
        ps0 = fmaf(v0, a2, ps0); ps1 = fmaf(v1, a2, ps1);
        ps2 = fmaf(v2, a2, ps2); ps3 = fmaf(v3, a2, ps3);
        pd0 = fmaf(v0, b2, pd0); pd1 = fmaf(v1, b2, pd1);
        pd2 = fmaf(v2, b2, pd2); pd3 = fmaf(v3, b2, pd3);
    }
    #pragma unroll
    for (int off = 1; off < 16; off <<= 1) {
        ps0 += __shfl_xor(ps0, off); ps1 += __shfl_xor(ps1, off);
        ps2 += __shfl_xor(ps2, off); ps3 += __shfl_xor(ps3, off);
        pd0 += __shfl_xor(pd0, off); pd1 += __shfl_xor(pd1, off);
        pd2 += __shfl_xor(pd2, off); pd3 += __shfl_xor(pd3, off);
    }
    if (lo == 0) {
        int nb = tile * 16 + quad * 4;
        s2[nb + 0] = ps0; s2[nb + 1] = ps1; s2[nb + 2] = ps2; s2[nb + 3] = ps3;
        d2[nb + 0] = pd0; d2[nb + 1] = pd1; d2[nb + 2] = pd2; d2[nb + 3] = pd3;
    }
}

// ---- K_logit2: 1-stage SW pipeline on edges load ----
__global__ __launch_bounds__(256) void k_logit2(
    const int* __restrict__ rowptr, const int2* __restrict__ edges,
    const float* __restrict__ s2, const float* __restrict__ d2,
    const float* __restrict__ ae2, half_t* __restrict__ p2)
{
    int w = (blockIdx.x * blockDim.x + threadIdx.x) >> 6;
    int lane = threadIdx.x & 63;
    if (w >= N_NODES) return;
    int jb = rowptr[w], je = rowptr[w + 1];
    if (jb >= je) return;
    float d2v = d2[w];
    float aev = ae2[0];
    int idx = jb + lane;
    int2 ed = edges[idx < je ? idx : jb];
    for (int base = jb; base < je; base += 64) {
        int nidx = idx + 64;
        int2 ned = edges[nidx < je ? nidx : jb];   // prefetch next group
        if (idx < je) {
            float l = lrelu(s2[ed.x] + d2v + __int_as_float(ed.y) * aev);
            p2[idx] = (half_t)__expf(l);
        }
        ed = ned; idx = nidx;
    }
}

// ---- K_node2: LDS-staged edge list -> independent gathers + fused
//      log_softmax epilogue ----
__global__ __launch_bounds__(256) void k_node2(
    const int* __restrict__ rowptr, const int2* __restrict__ edges,
    const half_t* __restrict__ p2, const ushort_t* __restrict__ H2,
    float* __restrict__ out)
{
    __shared__ int2 sp[4][64];            // (src, p_float_bits) per wave
    int w = (blockIdx.x * blockDim.x + threadIdx.x) >> 6;
    int lane = threadIdx.x & 63;
    int wv = (threadIdx.x >> 6) & 3;
    if (w >= N_NODES) return;
    int c = lane < C2 ? lane : 0;
    int jb = rowptr[w], je = rowptr[w + 1];
    float den0 = 0.f, den1 = 0.f;
    float acc0 = 0.f, acc1 = 0.f;
    const ushort_t* H2c = H2 + c;
    for (int base = jb; base < je; base += 64) {
        int idx = base + lane;
        int s = 0; float p = 0.f;
        if (idx < je) {
            s = edges[idx].x;
            p = (float)p2[idx];
        }
        sp[wv][lane] = make_int2(s, __float_as_int(p));
        __builtin_amdgcn_wave_barrier();
        int cnt = min(64, je - base);
        int cnt4 = (cnt + 3) & ~3;          // pad edges have p=0 -> contribute 0
        for (int e = 0; e < cnt4; e += 4) {
            int2 e0 = sp[wv][e + 0];
            int2 e1 = sp[wv][e + 1];
            int2 e2 = sp[wv][e + 2];
            int2 e3 = sp[wv][e + 3];
            float h0  = bf2f(H2c[(size_t)e0.x * C1]);
            float h1  = bf2f(H2c[(size_t)e1.x * C1]);
            float h2_ = bf2f(H2c[(size_t)e2.x * C1]);
            float h3  = bf2f(H2c[(size_t)e3.x * C1]);
            float p0  = __int_as_float(e0.y);
            float p1v = __int_as_float(e1.y);
            float p2v = __int_as_float(e2.y);
            float p3  = __int_as_float(e3.y);
            den0 += p0 + p1v;
            den1 += p2v + p3;
            acc0 = fmaf(p0,  h0,  fmaf(p1v, h1, acc0));
            acc1 = fmaf(p2v, h2_, fmaf(p3,  h3, acc1));
        }
        __builtin_amdgcn_wave_barrier();
    }
    float den = den0 + den1;
    float acc = acc0 + acc1;
    float o = acc / (den + 1e-16f);
    float v = lane < C2 ? o : -INFINITY;
    float m = v;
    #pragma unroll
    for (int off = 32; off; off >>= 1) m = fmaxf(m, __shfl_xor(m, off));
    float p = lane < C2 ? __expf(v - m) : 0.f;
    #pragma unroll
    for (int off = 32; off; off >>= 1) p += __shfl_xor(p, off);
    float ls = __logf(p);
    if (lane < C2) out[(size_t)w * C2 + lane] = v - m - ls;
}

extern "C" void kernel_launch(void* const* d_in, const int* in_sizes, int n_in,
                              void* d_out, int out_size, void* d_ws, size_t ws_size,
                              hipStream_t stream)
{
    const float* x   = (const float*)d_in[0];
    const int*   ei  = (const int*)  d_in[1];
    const float* ea  = (const float*)d_in[2];
    const float* W1  = (const float*)d_in[3];
    const float* as1 = (const float*)d_in[4];
    const float* ad1 = (const float*)d_in[5];
    const float* ae1 = (const float*)d_in[6];
    const float* W2  = (const float*)d_in[7];
    const float* as2 = (const float*)d_in[8];
    const float* ad2 = (const float*)d_in[9];
    const float* ae2 = (const float*)d_in[10];
    float* out = (float*)d_out;

    // workspace layout (4-byte units), aliased to stay <= 72 MB:
    //   H1 [0,3.2M) dead after k_node1 -> reused as H2 (k_gemm2 writes)
    //   out1r in [3.2M,6.4M)
    //   xb (bf16 x, 6.4M words) in the p1 slot [9.6M,16.0M): dead after
    //     k_gemm1_mfma; then deg/rank alias it (memset AFTER gemm1!), then
    //     p1 overwrites (k_logit1)
    //   p2 aliases s1 (dead after k_logit1)
    //   rowptr needs 100,001 ints -> s2 starts 8 words later (R5 lesson)
    float*    ws     = (float*)d_ws;
    ushort_t* H1     = (ushort_t*)ws;                 // [0, 3.2M)  bf16
    ushort_t* H2     = (ushort_t*)ws;                 //   alias (after node1)
    ushort_t* out1r  = (ushort_t*)(ws + 3200000);     // [3.2M, 6.4M)
    int2*     edges  = (int2*)(ws + 6400000);         // [6.4M, 9.6M)
    ushort_t* xb     = (ushort_t*)(ws + 9600000);     // [9.6M, 16.0M) bf16 x
    half_t*   p1     = (half_t*)(ws + 9600000);       //   alias (after gemm1)
    int*      deg    = (int*)(ws + 9600000);          //   alias (after gemm1)
    int*      rank   = (int*)(ws + 9700000);          //   alias
    int*      bsum   = (int*)(ws + 11300000);         //   alias (391)
    int*      boff   = (int*)(ws + 11301000);         //   alias (391)
    float*    s1     = ws + 16000000;                 // [16.0M, 16.8M)
    half_t*   p2     = (half_t*)(ws + 16000000);      //   alias
    float*    d1     = ws + 16800000;                 // [16.8M, 17.6M)
    int*      rowptr = (int*)(ws + 17600000);         // 100,001 ints
    float*    s2     = ws + 17700008;                 // 100,000
    float*    d2     = ws + 17800008;                 // 100,000
    ushort_t* W2p    = (ushort_t*)(ws + 17900008);    // 3072 bf16 (1536 w)
    ushort_t* W1p    = (ushort_t*)(ws + 17901544);    // 8192 bf16 (4096 w)

    k_xcast     <<<N_NODES * IN_F / (256 * 8), 256, 0, stream>>>(x, xb);
    k_w1prep    <<<32, 256, 0, stream>>>(W1, W1p);
    k_w2prep    <<<12, 256, 0, stream>>>(W2, W2p);
    k_gemm1_mfma<<<(N_NODES / 16 + 3) / 4, 256, 0, stream>>>(xb, W1p, H1);
    k_sd1       <<<(N_NODES + 3) / 4, 256, 0, stream>>>(H1, as1, ad1, s1, d1);
    hipMemsetAsync(deg, 0, 100000 * 4, stream);       // AFTER gemm1 (xb alias)
    k_count     <<<(N_EDGES + 255) / 256, 256, 0, stream>>>(ei, deg, rank);
    k_red       <<<N_SBLK, SCAN_B, 0, stream>>>(deg, bsum);
    k_scan_small<<<1, 512, 0, stream>>>(bsum, boff, rowptr);
    k_apply     <<<N_SBLK, SCAN_B, 0, stream>>>(deg, boff, rowptr);
    k_fill      <<<(N_EDGES + 255) / 256, 256, 0, stream>>>(ei, ea, rowptr, rank, edges);
    k_logit1    <<<(N_NODES + 3) / 4, 256, 0, stream>>>(rowptr, edges, s1, d1, ae1, p1);
    k_node1     <<<(N_NODES + 3) / 4, 256, 0, stream>>>(rowptr, edges, p1, H1, out1r);
    k_gemm2     <<<(N_NODES / 16 + 3) / 4, 256, 0, stream>>>(out1r, W2p, as2, ad2,
                                                             H2, s2, d2);
    k_logit2    <<<(N_NODES + 3) / 4, 256, 0, stream>>>(rowptr, edges, s2, d2, ae2, p2);
    k_node2     <<<(N_NODES + 3) / 4, 256, 0, stream>>>(rowptr, edges, p2, H2, out);
}

// Round 2
// 391.477 us; speedup vs baseline: 1.1733x; 1.0898x over previous
//
#include <hip/hip_runtime.h>
#include <math.h>

#define N_NODES 100000
#define N_EDGES 1600000
#define IN_F    128
#define NH1     8
#define HID     8
#define C1      64   // NH1*HID
#define C2      40   // N_CLASSES

// counting-sort CSR build
#define EB      4096                     // edges per block (pass A/C)
#define B1      ((N_EDGES + EB - 1) / EB)          // 391 blocks
#define NBIN    ((N_NODES + 255) / 256)            // 391 coarse bins (dst>>8)

typedef unsigned short ushort_t;
typedef unsigned int uint_t;
typedef _Float16 half_t;
typedef short short8 __attribute__((ext_vector_type(8)));
typedef float f32x4 __attribute__((ext_vector_type(4)));

__device__ __forceinline__ float lrelu(float x) { return x > 0.f ? x : 0.2f * x; }
__device__ __forceinline__ ushort_t f2bf(float f) {
    uint_t u = __float_as_uint(f);
    u = (u + 0x7FFFu + ((u >> 16) & 1u)) >> 16;   // round-to-nearest-even
    return (ushort_t)u;
}
__device__ __forceinline__ float bf2f(ushort_t s) {
    return __uint_as_float(((uint_t)s) << 16);
}

// ---- x -> bf16 cast (streaming, 8 elems/thread) ----
__global__ __launch_bounds__(256) void k_xcast(
    const float* __restrict__ x, ushort_t* __restrict__ xb)
{
    size_t i8 = (size_t)(blockIdx.x * 256 + threadIdx.x) * 8;   // 12.8M total
    float4 a = *(const float4*)(x + i8);
    float4 b = *(const float4*)(x + i8 + 4);
    ushort_t o[8] = {f2bf(a.x), f2bf(a.y), f2bf(a.z), f2bf(a.w),
                     f2bf(b.x), f2bf(b.y), f2bf(b.z), f2bf(b.w)};
    *(int4*)(xb + i8) = *(const int4*)o;
}

// ---- W1 pre-swizzle: B-frags for mfma_f32_16x16x32_bf16 ----
__global__ __launch_bounds__(256) void k_w1prep(
    const float* __restrict__ W1, ushort_t* __restrict__ W1p)
{
    int i = blockIdx.x * 256 + threadIdx.x;     // 8192
    if (i >= 8192) return;
    int j = i & 7, lane = (i >> 3) & 63, nt = (i >> 9) & 3, s = i >> 11;
    int k = s * 32 + (lane >> 4) * 8 + j;
    int n = nt * 16 + (lane & 15);
    W1p[i] = f2bf(W1[k * C1 + n]);
}

// ---- GEMM1 (MFMA): H1[100k x 64] = xb[100k x 128] @ W1 ----
__global__ __launch_bounds__(256) void k_gemm1_mfma(
    const ushort_t* __restrict__ xb, const ushort_t* __restrict__ W1p,
    ushort_t* __restrict__ H1)
{
    int tile = (blockIdx.x * blockDim.x + threadIdx.x) >> 6;
    int lane = threadIdx.x & 63;
    if (tile >= N_NODES / 16) return;
    int quad = lane >> 4, lo = lane & 15;
    const ushort_t* arow = xb + ((size_t)tile * 16 + lo) * IN_F + quad * 8;
    short8 a0 = *(const short8*)arow;            // k = 0*32 + quad*8+j
    short8 a1 = *(const short8*)(arow + 32);
    short8 a2 = *(const short8*)(arow + 64);
    short8 a3 = *(const short8*)(arow + 96);
    f32x4 acc[4] = {{0,0,0,0},{0,0,0,0},{0,0,0,0},{0,0,0,0}};
    #pragma unroll
    for (int nt = 0; nt < 4; ++nt) {
        short8 b0 = *(const short8*)&W1p[((0 * 4 + nt) * 64 + lane) * 8];
        short8 b1 = *(const short8*)&W1p[((1 * 4 + nt) * 64 + lane) * 8];
        short8 b2 = *(const short8*)&W1p[((2 * 4 + nt) * 64 + lane) * 8];
        short8 b3 = *(const short8*)&W1p[((3 * 4 + nt) * 64 + lane) * 8];
        acc[nt] = __builtin_amdgcn_mfma_f32_16x16x32_bf16(a0, b0, acc[nt], 0, 0, 0);
        acc[nt] = __builtin_amdgcn_mfma_f32_16x16x32_bf16(a1, b1, acc[nt], 0, 0, 0);
        acc[nt] = __builtin_amdgcn_mfma_f32_16x16x32_bf16(a2, b2, acc[nt], 0, 0, 0);
        acc[nt] = __builtin_amdgcn_mfma_f32_16x16x32_bf16(a3, b3, acc[nt], 0, 0, 0);
    }
    int nb = tile * 16 + quad * 4;               // C/D: col=lo, row=quad*4+reg
    #pragma unroll
    for (int nt = 0; nt < 4; ++nt) {
        int cb = nt * 16 + lo;
        #pragma unroll
        for (int r = 0; r < 4; ++r)
            H1[(size_t)(nb + r) * C1 + cb] = f2bf(acc[nt][r]);
    }
}

// ---- s1/d1 dots from H1: wave per node, lane = h*8+f ----
__global__ __launch_bounds__(256) void k_sd1(
    const ushort_t* __restrict__ H1,
    const float* __restrict__ as1, const float* __restrict__ ad1,
    float* __restrict__ s1, float* __restrict__ d1)
{
    int n = (blockIdx.x * blockDim.x + threadIdx.x) >> 6;
    int lane = threadIdx.x & 63;
    if (n >= N_NODES) return;
    float h = bf2f(H1[(size_t)n * C1 + lane]);
    float ps = h * as1[lane], pd = h * ad1[lane];
    #pragma unroll
    for (int off = 4; off; off >>= 1) {
        ps += __shfl_xor(ps, off);
        pd += __shfl_xor(pd, off);
    }
    if ((lane & 7) == 0) {
        s1[n * NH1 + (lane >> 3)] = ps;
        d1[n * NH1 + (lane >> 3)] = pd;
    }
}

// ---- W2 pre-swizzle ----
__global__ __launch_bounds__(256) void k_w2prep(
    const float* __restrict__ W2, ushort_t* __restrict__ W2p)
{
    int i = blockIdx.x * 256 + threadIdx.x;
    if (i >= 3072) return;
    int j = i & 7, lane = (i >> 3) & 63, khalf = (i >> 9) & 1, nt = i >> 10;
    int n = nt * 16 + (lane & 15);
    int k = khalf * 32 + (lane >> 4) * 8 + j;
    float v = (n < C2) ? W2[k * C2 + n] : 0.f;
    W2p[i] = f2bf(v);
}

// ============ counting-sort CSR build (no global atomics) ============

// ---- pass A: per-block LDS histogram over coarse bins (dst>>8).
//      Transposed layout: Hblk[bin*B1 + blk] so colscan loads coalesced. ----
__global__ __launch_bounds__(256) void k_hist1(
    const int* __restrict__ ei, int* __restrict__ Hblk)
{
    __shared__ int h[NBIN];
    for (int i = threadIdx.x; i < NBIN; i += 256) h[i] = 0;
    __syncthreads();
    int base = blockIdx.x * EB;
    for (int i = threadIdx.x; i < EB; i += 256) {
        int idx = base + i;
        if (idx < N_EDGES) atomicAdd(&h[ei[N_EDGES + idx] >> 8], 1);
    }
    __syncthreads();
    for (int i = threadIdx.x; i < NBIN; i += 256)
        Hblk[i * B1 + blockIdx.x] = h[i];
}

// ---- pass B1: per-bin exclusive scan over blocks (in place) + bin totals ----
__global__ __launch_bounds__(512) void k_colscan(
    int* __restrict__ Hblk, int* __restrict__ totB)
{
    __shared__ int s[512];
    int bin = blockIdx.x, t = threadIdx.x;
    int v = (t < B1) ? Hblk[bin * B1 + t] : 0;
    s[t] = v;
    __syncthreads();
    for (int off = 1; off < 512; off <<= 1) {
        int u = (t >= off) ? s[t - off] : 0;
        __syncthreads();
        s[t] += u;
        __syncthreads();
    }
    if (t < B1) Hblk[bin * B1 + t] = s[t] - v;     // exclusive within column
    if (t == 511) totB[bin] = s[511];
}

// ---- pass B2: exclusive scan of bin totals -> bucket bases ----
__global__ __launch_bounds__(512) void k_basescan(
    const int* __restrict__ totB, int* __restrict__ baseB,
    int* __restrict__ rowptr)
{
    __shared__ int s[512];
    int t = threadIdx.x;
    int v = (t < NBIN) ? totB[t] : 0;
    s[t] = v;
    __syncthreads();
    for (int off = 1; off < 512; off <<= 1) {
        int u = (t >= off) ? s[t - off] : 0;
        __syncthreads();
        s[t] += u;
        __syncthreads();
    }
    if (t < NBIN) baseB[t] = s[t] - v;
    if (t == 511) { baseB[NBIN] = s[511]; rowptr[N_NODES] = s[511]; }
}

// ---- pass C: replay edges, LDS-atomic local rank -> coarse-bucketed
//      int4 (src, dst, ea_bits, 0). Slot ranges exclusive per (block,bin). ----
__global__ __launch_bounds__(256) void k_scatter1(
    const int* __restrict__ ei, const float* __restrict__ ea,
    const int* __restrict__ Hblk, const int* __restrict__ baseB,
    int4* __restrict__ coarse)
{
    __shared__ int h[NBIN];
    for (int i = threadIdx.x; i < NBIN; i += 256) h[i] = 0;
    __syncthreads();
    int base = blockIdx.x * EB;
    for (int i = threadIdx.x; i < EB; i += 256) {
        int idx = base + i;
        if (idx < N_EDGES) {
            int d = ei[N_EDGES + idx];
            int bin = d >> 8;
            int lr = atomicAdd(&h[bin], 1);
            int pos = baseB[bin] + Hblk[bin * B1 + blockIdx.x] + lr;
            coarse[pos] = make_int4(ei[idx], d, __float_as_int(ea[idx]), 0);
        }
    }
}

// ---- pass D: one block per coarse bucket. 256-bin LDS hist + block scan ->
//      rowptr for the bucket's 256 nodes; second pass scatters final int2
//      edges into the bucket's L2-local window. No per-bucket size cap. ----
__global__ __launch_bounds__(256) void k_scatter2(
    const int4* __restrict__ coarse, const int* __restrict__ baseB,
    int2* __restrict__ edges, int* __restrict__ rowptr)
{
    __shared__ int h[256];
    __shared__ int sc[256];
    __shared__ int offx[256];
    int bin = blockIdx.x, t = threadIdx.x;
    int s0 = baseB[bin], s1 = baseB[bin + 1];
    h[t] = 0;
    __syncthreads();
    for (int j = s0 + t; j < s1; j += 256)
        atomicAdd(&h[coarse[j].y & 255], 1);
    __syncthreads();
    int v = h[t];
    sc[t] = v;
    __syncthreads();
    for (int off = 1; off < 256; off <<= 1) {
        int u = (t >= off) ? sc[t - off] : 0;
        __syncthreads();
        sc[t] += u;
        __syncthreads();
    }
    offx[t] = sc[t] - v;          // exclusive scan of per-node counts
    int node = bin * 256 + t;
    if (node < N_NODES) rowptr[node] = s0 + offx[t];
    h[t] = 0;
    __syncthreads();
    for (int j = s0 + t; j < s1; j += 256) {
        int4 c = coarse[j];
        int ln = c.y & 255;
        int lr = atomicAdd(&h[ln], 1);
        edges[s0 + offx[ln] + lr] = make_int2(c.x, c.z);
    }
}

// ============ attention / aggregation (unchanged from R1) ============

// ---- K_logit1: p1 AoS [E][8] fp16. 1-stage SW pipeline on edges load ----
__global__ __launch_bounds__(256) void k_logit1(
    const int* __restrict__ rowptr, const int2* __restrict__ edges,
    const float* __restrict__ s1, const float* __restrict__ d1,
    const float* __restrict__ ae1, half_t* __restrict__ p1)
{
    int w = (blockIdx.x * blockDim.x + threadIdx.x) >> 6;
    int lane = threadIdx.x & 63;
    if (w >= N_NODES) return;
    int hL = lane & 7, eL = lane >> 3;
    int jb = rowptr[w], je = rowptr[w + 1];
    if (jb >= je) return;
    float d1L = d1[w * NH1 + hL];
    float aeL = ae1[hL];
    int idx = jb + eL;
    int2 ed = edges[idx < je ? idx : jb];
    for (int base = jb; base < je; base += 8) {
        int nidx = idx + 8;
        int2 ned = edges[nidx < je ? nidx : jb];   // prefetch next group
        bool valid = idx < je;
        float l = lrelu(s1[ed.x * NH1 + hL] + d1L + __int_as_float(ed.y) * aeL);
        if (valid) p1[(size_t)idx * NH1 + hL] = (half_t)__expf(l);
        ed = ned; idx = nidx;
    }
}

// ---- K_node1: LDS-staged edge list -> independent gathers ----
__global__ __launch_bounds__(256) void k_node1(
    const int* __restrict__ rowptr, const int2* __restrict__ edges,
    const half_t* __restrict__ p1, const ushort_t* __restrict__ H1,
    ushort_t* __restrict__ out1r)
{
    __shared__ int    sm_s[4][64];
    __shared__ half_t sm_p[4][64 * 8];    // [e*8 + h]
    int w = (blockIdx.x * blockDim.x + threadIdx.x) >> 6;
    int lane = threadIdx.x & 63;
    int wv = (threadIdx.x >> 6) & 3;
    if (w >= N_NODES) return;
    int hA = lane >> 3;
    int jb = rowptr[w], je = rowptr[w + 1];
    float den0 = 0.f, den1 = 0.f;
    float acc0 = 0.f, acc1 = 0.f;
    const ushort_t* H1c = H1 + lane;
    const half_t* pp = &sm_p[wv][hA];
    for (int base = jb; base < je; base += 64) {
        int idx = base + lane;
        int s = 0;
        int4 pv = make_int4(0, 0, 0, 0);
        if (idx < je) {
            s = edges[idx].x;
            pv = *(const int4*)(p1 + (size_t)idx * NH1);   // 8 halves of this edge
        }
        sm_s[wv][lane] = s;
        *(int4*)&sm_p[wv][lane * 8] = pv;
        __builtin_amdgcn_wave_barrier();
        int cnt = min(64, je - base);
        int cnt4 = (cnt + 3) & ~3;          // pad edges have p=0 -> contribute 0
        for (int e = 0; e < cnt4; e += 4) {
            int s0  = sm_s[wv][e + 0];
            int s1_ = sm_s[wv][e + 1];
            int s2_ = sm_s[wv][e + 2];
            int s3  = sm_s[wv][e + 3];
            float p0  = (float)pp[(e + 0) * 8];
            float p1v = (float)pp[(e + 1) * 8];
            float p2v = (float)pp[(e + 2) * 8];
            float p3  = (float)pp[(e + 3) * 8];
            float h0  = bf2f(H1c[(size_t)s0  * C1]);
            float h1  = bf2f(H1c[(size_t)s1_ * C1]);
            float h2_ = bf2f(H1c[(size_t)s2_ * C1]);
            float h3  = bf2f(H1c[(size_t)s3  * C1]);
            den0 += p0 + p1v;
            den1 += p2v + p3;
            acc0 = fmaf(p0,  h0,  fmaf(p1v, h1, acc0));
            acc1 = fmaf(p2v, h2_, fmaf(p3,  h3, acc1));
        }
        __builtin_amdgcn_wave_barrier();
    }
    float den = den0 + den1;
    float acc = acc0 + acc1;
    float o = acc / (den + 1e-16f);
    float r = o > 0.f ? o : __expf(o) - 1.f;   // elu
    out1r[(size_t)w * C1 + lane] = f2bf(r);
}

// ---- K_gemm2 (MFMA): H2 = out1r @ W2 + s2/d2 dots ----
__global__ __launch_bounds__(256) void k_gemm2(
    const ushort_t* __restrict__ out1r, const ushort_t* __restrict__ W2p,
    const float* __restrict__ as2, const float* __restrict__ ad2,
    ushort_t* __restrict__ H2, float* __restrict__ s2, float* __restrict__ d2)
{
    int tile = (blockIdx.x * blockDim.x + threadIdx.x) >> 6;
    int lane = threadIdx.x & 63;
    if (tile >= N_NODES / 16) return;
    int quad = lane >> 4, lo = lane & 15;
    const ushort_t* arow = out1r + ((size_t)tile * 16 + lo) * C1 + quad * 8;
    short8 a0 = *(const short8*)arow;
    short8 a1 = *(const short8*)(arow + 32);
    f32x4 acc[3] = {{0,0,0,0},{0,0,0,0},{0,0,0,0}};
    #pragma unroll
    for (int nt = 0; nt < 3; ++nt) {
        short8 b0 = *(const short8*)&W2p[((nt * 2 + 0) * 64 + lane) * 8];
        short8 b1 = *(const short8*)&W2p[((nt * 2 + 1) * 64 + lane) * 8];
        acc[nt] = __builtin_amdgcn_mfma_f32_16x16x32_bf16(a0, b0, acc[nt], 0, 0, 0);
        acc[nt] = __builtin_amdgcn_mfma_f32_16x16x32_bf16(a1, b1, acc[nt], 0, 0, 0);
    }
    float ps0 = 0.f, ps1 = 0.f, ps2 = 0.f, ps3 = 0.f;
    float pd0 = 0.f, pd1 = 0.f, pd2 = 0.f, pd3 = 0.f;
    #pragma unroll
    for (int nt = 0; nt < 3; ++nt) {
        int cb = nt * 16 + lo;
        float a2 = cb < C2 ? as2[cb] : 0.f;
        float b2 = cb < C2 ? ad2[cb] : 0.f;
        float v0 = acc[nt][0], v1 = acc[nt][1], v2 = acc[nt][2], v3 = acc[nt][3];
        int nb = tile * 16 + quad * 4;
        H2[(size_t)(nb + 0) * C1 + cb] = f2bf(v0);
        H2[(size_t)(nb + 1) * C1 + cb] = f2bf(v1);
        H2[(size_t)(nb + 2) * C1 + cb] = f2bf(v2);
        H2[(size_t)(nb + 3) * C1 + cb] = f2bf(v3);
        ps0 = fmaf(v0, a2, ps0); ps1 = fmaf(v1, a2, ps1);
        ps2 = fmaf(v2, a2, ps2); ps3 = fmaf(v3, a2, ps3);
        pd0 = fmaf(v0, b2, pd0); pd1 = fmaf(v1, b2, pd1);
        pd2 = fmaf(v2, b2, pd2); pd3 = fmaf(v3, b2, pd3);
    }
    #pragma unroll
    for (int off = 1; off < 16; off <<= 1) {
        ps0 += __shfl_xor(ps0, off); ps1 += __shfl_xor(ps1, off);
        ps2 += __shfl_xor(ps2, off); ps3 += __shfl_xor(ps3, off);
        pd0 += __shfl_xor(pd0, off); pd1 += __shfl_xor(pd1, off);
        pd2 += __shfl_xor(pd2, off); pd3 += __shfl_xor(pd3, off);
    }
    if (lo == 0) {
        int nb = tile * 16 + quad * 4;
        s2[nb + 0] = ps0; s2[nb + 1] = ps1; s2[nb + 2] = ps2; s2[nb + 3] = ps3;
        d2[nb + 0] = pd0; d2[nb + 1] = pd1; d2[nb + 2] = pd2; d2[nb + 3] = pd3;
    }
}

// ---- K_logit2: 1-stage SW pipeline on edges load ----
__global__ __launch_bounds__(256) void k_logit2(
    const int* __restrict__ rowptr, const int2* __restrict__ edges,
    const float* __restrict__ s2, const float* __restrict__ d2,
    const float* __restrict__ ae2, half_t* __restrict__ p2)
{
    int w = (blockIdx.x * blockDim.x + threadIdx.x) >> 6;
    int lane = threadIdx.x & 63;
    if (w >= N_NODES) return;
    int jb = rowptr[w], je = rowptr[w + 1];
    if (jb >= je) return;
    float d2v = d2[w];
    float aev = ae2[0];
    int idx = jb + lane;
    int2 ed = edges[idx < je ? idx : jb];
    for (int base = jb; base < je; base += 64) {
        int nidx = idx + 64;
        int2 ned = edges[nidx < je ? nidx : jb];   // prefetch next group
        if (idx < je) {
            float l = lrelu(s2[ed.x] + d2v + __int_as_float(ed.y) * aev);
            p2[idx] = (half_t)__expf(l);
        }
        ed = ned; idx = nidx;
    }
}

// ---- K_node2: LDS-staged edge list -> independent gathers + fused
//      log_softmax epilogue ----
__global__ __launch_bounds__(256) void k_node2(
    const int* __restrict__ rowptr, const int2* __restrict__ edges,
    const half_t* __restrict__ p2, const ushort_t* __restrict__ H2,
    float* __restrict__ out)
{
    __shared__ int2 sp[4][64];            // (src, p_float_bits) per wave
    int w = (blockIdx.x * blockDim.x + threadIdx.x) >> 6;
    int lane = threadIdx.x & 63;
    int wv = (threadIdx.x >> 6) & 3;
    if (w >= N_NODES) return;
    int c = lane < C2 ? lane : 0;
    int jb = rowptr[w], je = rowptr[w + 1];
    float den0 = 0.f, den1 = 0.f;
    float acc0 = 0.f, acc1 = 0.f;
    const ushort_t* H2c = H2 + c;
    for (int base = jb; base < je; base += 64) {
        int idx = base + lane;
        int s = 0; float p = 0.f;
        if (idx < je) {
            s = edges[idx].x;
            p = (float)p2[idx];
        }
        sp[wv][lane] = make_int2(s, __float_as_int(p));
        __builtin_amdgcn_wave_barrier();
        int cnt = min(64, je - base);
        int cnt4 = (cnt + 3) & ~3;          // pad edges have p=0 -> contribute 0
        for (int e = 0; e < cnt4; e += 4) {
            int2 e0 = sp[wv][e + 0];
            int2 e1 = sp[wv][e + 1];
            int2 e2 = sp[wv][e + 2];
            int2 e3 = sp[wv][e + 3];
            float h0  = bf2f(H2c[(size_t)e0.x * C1]);
            float h1  = bf2f(H2c[(size_t)e1.x * C1]);
            float h2_ = bf2f(H2c[(size_t)e2.x * C1]);
            float h3  = bf2f(H2c[(size_t)e3.x * C1]);
            float p0  = __int_as_float(e0.y);
            float p1v = __int_as_float(e1.y);
            float p2v = __int_as_float(e2.y);
            float p3  = __int_as_float(e3.y);
            den0 += p0 + p1v;
            den1 += p2v + p3;
            acc0 = fmaf(p0,  h0,  fmaf(p1v, h1, acc0));
            acc1 = fmaf(p2v, h2_, fmaf(p3,  h3, acc1));
        }
        __builtin_amdgcn_wave_barrier();
    }
    float den = den0 + den1;
    float acc = acc0 + acc1;
    float o = acc / (den + 1e-16f);
    float v = lane < C2 ? o : -INFINITY;
    float m = v;
    #pragma unroll
    for (int off = 32; off; off >>= 1) m = fmaxf(m, __shfl_xor(m, off));
    float p = lane < C2 ? __expf(v - m) : 0.f;
    #pragma unroll
    for (int off = 32; off; off >>= 1) p += __shfl_xor(p, off);
    float ls = __logf(p);
    if (lane < C2) out[(size_t)w * C2 + lane] = v - m - ls;
}

extern "C" void kernel_launch(void* const* d_in, const int* in_sizes, int n_in,
                              void* d_out, int out_size, void* d_ws, size_t ws_size,
                              hipStream_t stream)
{
    const float* x   = (const float*)d_in[0];
    const int*   ei  = (const int*)  d_in[1];
    const float* ea  = (const float*)d_in[2];
    const float* W1  = (const float*)d_in[3];
    const float* as1 = (const float*)d_in[4];
    const float* ad1 = (const float*)d_in[5];
    const float* ae1 = (const float*)d_in[6];
    const float* W2  = (const float*)d_in[7];
    const float* as2 = (const float*)d_in[8];
    const float* ad2 = (const float*)d_in[9];
    const float* ae2 = (const float*)d_in[10];
    float* out = (float*)d_out;

    // workspace layout (4-byte units), aliased to stay <= 72 MB:
    //   H1 [0,3.2M) dead after k_node1 -> reused as H2 (k_gemm2 writes)
    //   out1r region [3.2M,6.4M): free until k_node1 -> Hblk/totB/baseB
    //     (CSR-build temps, dead after k_scatter2) live there first
    //   edges (final CSR int2) in [6.4M,9.6M)
    //   xb (bf16 x) in [9.6M,16.0M): dead after k_gemm1_mfma; coarse
    //     (int4 bucketed edges) aliases it; p1 overwrites after scatter2
    //   p2 aliases s1 (dead after k_logit1)
    //   rowptr needs 100,001 ints -> s2 starts 8 words later
    float*    ws     = (float*)d_ws;
    ushort_t* H1     = (ushort_t*)ws;                 // [0, 3.2M)  bf16
    ushort_t* H2     = (ushort_t*)ws;                 //   alias (after node1)
    ushort_t* out1r  = (ushort_t*)(ws + 3200000);     // [3.2M, 6.4M)
    int*      Hblk   = (int*)(ws + 3200000);          //   alias: 391*391 ints
    int*      totB   = (int*)(ws + 3360000);          //   alias: 391 ints
    int*      baseB  = (int*)(ws + 3361000);          //   alias: 392 ints
    int2*     edges  = (int2*)(ws + 6400000);         // [6.4M, 9.6M)
    ushort_t* xb     = (ushort_t*)(ws + 9600000);     // [9.6M, 16.0M) bf16 x
    int4*     coarse = (int4*)(ws + 9600000);         //   alias (after gemm1)
    half_t*   p1     = (half_t*)(ws + 9600000);       //   alias (after scatter2)
    float*    s1     = ws + 16000000;                 // [16.0M, 16.8M)
    half_t*   p2     = (half_t*)(ws + 16000000);      //   alias
    float*    d1     = ws + 16800000;                 // [16.8M, 17.6M)
    int*      rowptr = (int*)(ws + 17600000);         // 100,001 ints
    float*    s2     = ws + 17700008;                 // 100,000
    float*    d2     = ws + 17800008;                 // 100,000
    ushort_t* W2p    = (ushort_t*)(ws + 17900008);    // 3072 bf16 (1536 w)
    ushort_t* W1p    = (ushort_t*)(ws + 17901544);    // 8192 bf16 (4096 w)

    k_xcast     <<<N_NODES * IN_F / (256 * 8), 256, 0, stream>>>(x, xb);
    k_w1prep    <<<32, 256, 0, stream>>>(W1, W1p);
    k_w2prep    <<<12, 256, 0, stream>>>(W2, W2p);
    k_gemm1_mfma<<<(N_NODES / 16 + 3) / 4, 256, 0, stream>>>(xb, W1p, H1);
    k_sd1       <<<(N_NODES + 3) / 4, 256, 0, stream>>>(H1, as1, ad1, s1, d1);
    // counting-sort CSR build (xb dead from here; coarse aliases it)
    k_hist1     <<<B1, 256, 0, stream>>>(ei, Hblk);
    k_colscan   <<<NBIN, 512, 0, stream>>>(Hblk, totB);
    k_basescan  <<<1, 512, 0, stream>>>(totB, baseB, rowptr);
    k_scatter1  <<<B1, 256, 0, stream>>>(ei, ea, Hblk, baseB, coarse);
    k_scatter2  <<<NBIN, 256, 0, stream>>>(coarse, baseB, edges, rowptr);
    // coarse dead from here; p1 aliases it
    k_logit1    <<<(N_NODES + 3) / 4, 256, 0, stream>>>(rowptr, edges, s1, d1, ae1, p1);
    k_node1     <<<(N_NODES + 3) / 4, 256, 0, stream>>>(rowptr, edges, p1, H1, out1r);
    k_gemm2     <<<(N_NODES / 16 + 3) / 4, 256, 0, stream>>>(out1r, W2p, as2, ad2,
                                                             H2, s2, d2);
    k_logit2    <<<(N_NODES + 3) / 4, 256, 0, stream>>>(rowptr, edges, s2, d2, ae2, p2);
    k_node2     <<<(N_NODES + 3) / 4, 256, 0, stream>>>(rowptr, edges, p2, H2, out);
}

// Round 3
// 333.711 us; speedup vs baseline: 1.3764x; 1.1731x over previous
//
#include <hip/hip_runtime.h>
#include <math.h>

#define N_NODES 100000
#define N_EDGES 1600000
#define IN_F    128
#define NH1     8
#define HID     8
#define C1      64   // NH1*HID
#define C2      40   // N_CLASSES

// counting-sort CSR build
#define EB      4096                     // edges per block (pass A/C)
#define B1      ((N_EDGES + EB - 1) / EB)          // 391 blocks
#define NBIN    ((N_NODES + 255) / 256)            // 391 coarse bins (dst>>8)

// prep grid split
#define XCAST_BLKS (N_NODES * IN_F / (256 * 8))    // 6250
#define WPREP_BLKS 44                              // ceil((8192+3072)/256)

typedef unsigned short ushort_t;
typedef unsigned int uint_t;
typedef _Float16 half_t;
typedef short short8 __attribute__((ext_vector_type(8)));
typedef float f32x4 __attribute__((ext_vector_type(4)));

__device__ __forceinline__ float lrelu(float x) { return x > 0.f ? x : 0.2f * x; }
__device__ __forceinline__ ushort_t f2bf(float f) {
    uint_t u = __float_as_uint(f);
    u = (u + 0x7FFFu + ((u >> 16) & 1u)) >> 16;   // round-to-nearest-even
    return (ushort_t)u;
}
__device__ __forceinline__ float bf2f(ushort_t s) {
    return __uint_as_float(((uint_t)s) << 16);
}
// 32-bit byte-offset gather of one bf16 from a uniform base
__device__ __forceinline__ float ldbf(const ushort_t* base, uint_t off_bytes) {
    return bf2f(*(const ushort_t*)((const char*)base + off_bytes));
}

// ---- merged prep: x->bf16 cast + W1/W2 pre-swizzle (one launch) ----
__global__ __launch_bounds__(256) void k_prep(
    const float* __restrict__ x, ushort_t* __restrict__ xb,
    const float* __restrict__ W1, ushort_t* __restrict__ W1p,
    const float* __restrict__ W2, ushort_t* __restrict__ W2p)
{
    int b = blockIdx.x;
    if (b < XCAST_BLKS) {
        size_t i8 = ((size_t)b * 256 + threadIdx.x) * 8;   // 12.8M total
        float4 a = *(const float4*)(x + i8);
        float4 c = *(const float4*)(x + i8 + 4);
        ushort_t o[8] = {f2bf(a.x), f2bf(a.y), f2bf(a.z), f2bf(a.w),
                         f2bf(c.x), f2bf(c.y), f2bf(c.z), f2bf(c.w)};
        *(int4*)(xb + i8) = *(const int4*)o;
        return;
    }
    int i = (b - XCAST_BLKS) * 256 + threadIdx.x;
    if (i < 8192) {
        // W1p[((s*4+nt)*64+lane)*8+j] = W1[k=s*32+(lane>>4)*8+j][n=nt*16+(lane&15)]
        int j = i & 7, lane = (i >> 3) & 63, nt = (i >> 9) & 3, s = i >> 11;
        int k = s * 32 + (lane >> 4) * 8 + j;
        int n = nt * 16 + (lane & 15);
        W1p[i] = f2bf(W1[k * C1 + n]);
    } else {
        int i2 = i - 8192;
        if (i2 < 3072) {
            int j = i2 & 7, lane = (i2 >> 3) & 63, khalf = (i2 >> 9) & 1, nt = i2 >> 10;
            int n = nt * 16 + (lane & 15);
            int k = khalf * 32 + (lane >> 4) * 8 + j;
            float v = (n < C2) ? W2[k * C2 + n] : 0.f;
            W2p[i2] = f2bf(v);
        }
    }
}

// ---- GEMM1 (MFMA): H1[100k x 64] = xb[100k x 128] @ W1, with fused
//      s1/d1 per-head dot epilogue (mirrors verified gemm2 pattern).
//      Head of feature cb = nt*2 + (lo>>3); per-head sum reduces over
//      lo&7 (8 lanes) via shfl_xor 1/2/4. ----
__global__ __launch_bounds__(256) void k_gemm1_mfma(
    const ushort_t* __restrict__ xb, const ushort_t* __restrict__ W1p,
    const float* __restrict__ as1, const float* __restrict__ ad1,
    ushort_t* __restrict__ H1, float* __restrict__ s1, float* __restrict__ d1)
{
    int tile = (blockIdx.x * blockDim.x + threadIdx.x) >> 6;
    int lane = threadIdx.x & 63;
    if (tile >= N_NODES / 16) return;
    int quad = lane >> 4, lo = lane & 15;
    const ushort_t* arow = xb + ((size_t)tile * 16 + lo) * IN_F + quad * 8;
    short8 a0 = *(const short8*)arow;            // k = 0*32 + quad*8+j
    short8 a1 = *(const short8*)(arow + 32);
    short8 a2 = *(const short8*)(arow + 64);
    short8 a3 = *(const short8*)(arow + 96);
    f32x4 acc[4] = {{0,0,0,0},{0,0,0,0},{0,0,0,0},{0,0,0,0}};
    #pragma unroll
    for (int nt = 0; nt < 4; ++nt) {
        short8 b0 = *(const short8*)&W1p[((0 * 4 + nt) * 64 + lane) * 8];
        short8 b1 = *(const short8*)&W1p[((1 * 4 + nt) * 64 + lane) * 8];
        short8 b2 = *(const short8*)&W1p[((2 * 4 + nt) * 64 + lane) * 8];
        short8 b3 = *(const short8*)&W1p[((3 * 4 + nt) * 64 + lane) * 8];
        acc[nt] = __builtin_amdgcn_mfma_f32_16x16x32_bf16(a0, b0, acc[nt], 0, 0, 0);
        acc[nt] = __builtin_amdgcn_mfma_f32_16x16x32_bf16(a1, b1, acc[nt], 0, 0, 0);
        acc[nt] = __builtin_amdgcn_mfma_f32_16x16x32_bf16(a2, b2, acc[nt], 0, 0, 0);
        acc[nt] = __builtin_amdgcn_mfma_f32_16x16x32_bf16(a3, b3, acc[nt], 0, 0, 0);
    }
    int nb = tile * 16 + quad * 4;               // C/D: col=lo, row=quad*4+reg
    float ps[4][4], pd[4][4];
    #pragma unroll
    for (int nt = 0; nt < 4; ++nt) {
        int cb = nt * 16 + lo;
        float av = as1[cb], dv = ad1[cb];
        #pragma unroll
        for (int r = 0; r < 4; ++r) {
            H1[(size_t)(nb + r) * C1 + cb] = f2bf(acc[nt][r]);
            ps[nt][r] = acc[nt][r] * av;
            pd[nt][r] = acc[nt][r] * dv;
        }
    }
    #pragma unroll
    for (int nt = 0; nt < 4; ++nt)
        #pragma unroll
        for (int r = 0; r < 4; ++r)
            #pragma unroll
            for (int off = 1; off < 8; off <<= 1) {
                ps[nt][r] += __shfl_xor(ps[nt][r], off);
                pd[nt][r] += __shfl_xor(pd[nt][r], off);
            }
    if ((lo & 7) == 0) {
        int hh = lo >> 3;
        #pragma unroll
        for (int nt = 0; nt < 4; ++nt) {
            int h = nt * 2 + hh;
            #pragma unroll
            for (int r = 0; r < 4; ++r) {
                s1[(nb + r) * NH1 + h] = ps[nt][r];
                d1[(nb + r) * NH1 + h] = pd[nt][r];
            }
        }
    }
}

// ============ counting-sort CSR build (no global atomics) ============

__global__ __launch_bounds__(256) void k_hist1(
    const int* __restrict__ ei, int* __restrict__ Hblk)
{
    __shared__ int h[NBIN];
    for (int i = threadIdx.x; i < NBIN; i += 256) h[i] = 0;
    __syncthreads();
    int base = blockIdx.x * EB;
    for (int i = threadIdx.x; i < EB; i += 256) {
        int idx = base + i;
        if (idx < N_EDGES) atomicAdd(&h[ei[N_EDGES + idx] >> 8], 1);
    }
    __syncthreads();
    for (int i = threadIdx.x; i < NBIN; i += 256)
        Hblk[i * B1 + blockIdx.x] = h[i];
}

__global__ __launch_bounds__(512) void k_colscan(
    int* __restrict__ Hblk, int* __restrict__ totB)
{
    __shared__ int s[512];
    int bin = blockIdx.x, t = threadIdx.x;
    int v = (t < B1) ? Hblk[bin * B1 + t] : 0;
    s[t] = v;
    __syncthreads();
    for (int off = 1; off < 512; off <<= 1) {
        int u = (t >= off) ? s[t - off] : 0;
        __syncthreads();
        s[t] += u;
        __syncthreads();
    }
    if (t < B1) Hblk[bin * B1 + t] = s[t] - v;     // exclusive within column
    if (t == 511) totB[bin] = s[511];
}

__global__ __launch_bounds__(512) void k_basescan(
    const int* __restrict__ totB, int* __restrict__ baseB,
    int* __restrict__ rowptr)
{
    __shared__ int s[512];
    int t = threadIdx.x;
    int v = (t < NBIN) ? totB[t] : 0;
    s[t] = v;
    __syncthreads();
    for (int off = 1; off < 512; off <<= 1) {
        int u = (t >= off) ? s[t - off] : 0;
        __syncthreads();
        s[t] += u;
        __syncthreads();
    }
    if (t < NBIN) baseB[t] = s[t] - v;
    if (t == 511) { baseB[NBIN] = s[511]; rowptr[N_NODES] = s[511]; }
}

__global__ __launch_bounds__(256) void k_scatter1(
    const int* __restrict__ ei, const float* __restrict__ ea,
    const int* __restrict__ Hblk, const int* __restrict__ baseB,
    int4* __restrict__ coarse)
{
    __shared__ int h[NBIN];
    for (int i = threadIdx.x; i < NBIN; i += 256) h[i] = 0;
    __syncthreads();
    int base = blockIdx.x * EB;
    for (int i = threadIdx.x; i < EB; i += 256) {
        int idx = base + i;
        if (idx < N_EDGES) {
            int d = ei[N_EDGES + idx];
            int bin = d >> 8;
            int lr = atomicAdd(&h[bin], 1);
            int pos = baseB[bin] + Hblk[bin * B1 + blockIdx.x] + lr;
            coarse[pos] = make_int4(ei[idx], d, __float_as_int(ea[idx]), 0);
        }
    }
}

__global__ __launch_bounds__(256) void k_scatter2(
    const int4* __restrict__ coarse, const int* __restrict__ baseB,
    int2* __restrict__ edges, int* __restrict__ rowptr)
{
    __shared__ int h[256];
    __shared__ int sc[256];
    __shared__ int offx[256];
    int bin = blockIdx.x, t = threadIdx.x;
    int s0 = baseB[bin], s1 = baseB[bin + 1];
    h[t] = 0;
    __syncthreads();
    for (int j = s0 + t; j < s1; j += 256)
        atomicAdd(&h[coarse[j].y & 255], 1);
    __syncthreads();
    int v = h[t];
    sc[t] = v;
    __syncthreads();
    for (int off = 1; off < 256; off <<= 1) {
        int u = (t >= off) ? sc[t - off] : 0;
        __syncthreads();
        sc[t] += u;
        __syncthreads();
    }
    offx[t] = sc[t] - v;          // exclusive scan of per-node counts
    int node = bin * 256 + t;
    if (node < N_NODES) rowptr[node] = s0 + offx[t];
    h[t] = 0;
    __syncthreads();
    for (int j = s0 + t; j < s1; j += 256) {
        int4 c = coarse[j];
        int ln = c.y & 255;
        int lr = atomicAdd(&h[ln], 1);
        edges[s0 + offx[ln] + lr] = make_int2(c.x, c.z);
    }
}

// ============ attention / aggregation ============

// ---- K_node1 with FUSED logit1: staging lane loads its edge, gathers the
//      s1 row (2x float4), computes 8 exp(lrelu(.)) and stages halves in
//      LDS. Inner loop: broadcast ds_read + 32-bit-offset H1 gathers. ----
__global__ __launch_bounds__(256) void k_node1(
    const int* __restrict__ rowptr, const int2* __restrict__ edges,
    const float* __restrict__ s1, const float* __restrict__ d1,
    const float* __restrict__ ae1,
    const ushort_t* __restrict__ H1, ushort_t* __restrict__ out1r)
{
    __shared__ int    sm_s[4][64];
    __shared__ half_t sm_p[4][64 * 8];    // [e*8 + h]
    int w = (blockIdx.x * blockDim.x + threadIdx.x) >> 6;
    int lane = threadIdx.x & 63;
    int wv = (threadIdx.x >> 6) & 3;
    if (w >= N_NODES) return;
    int hA = lane >> 3;
    int jb = rowptr[w], je = rowptr[w + 1];
    float4 d1a = *(const float4*)(d1 + w * NH1);       // uniform per node
    float4 d1b = *(const float4*)(d1 + w * NH1 + 4);
    float4 aea = *(const float4*)(ae1);
    float4 aeb = *(const float4*)(ae1 + 4);
    float den0 = 0.f, den1 = 0.f;
    float acc0 = 0.f, acc1 = 0.f;
    uint_t lb = (uint_t)lane << 1;                     // byte offset of lane's col
    const half_t* pp = &sm_p[wv][hA];
    for (int base = jb; base < je; base += 64) {
        int idx = base + lane;
        int s = 0;
        int4 pv = make_int4(0, 0, 0, 0);
        if (idx < je) {
            int2 ed = edges[idx];
            s = ed.x;
            float ea = __int_as_float(ed.y);
            const float* s1r = s1 + (size_t)s * NH1;
            float4 sa = *(const float4*)s1r;
            float4 sb = *(const float4*)(s1r + 4);
            half_t ph[8];
            ph[0] = (half_t)__expf(lrelu(fmaf(ea, aea.x, sa.x + d1a.x)));
            ph[1] = (half_t)__expf(lrelu(fmaf(ea, aea.y, sa.y + d1a.y)));
            ph[2] = (half_t)__expf(lrelu(fmaf(ea, aea.z, sa.z + d1a.z)));
            ph[3] = (half_t)__expf(lrelu(fmaf(ea, aea.w, sa.w + d1a.w)));
            ph[4] = (half_t)__expf(lrelu(fmaf(ea, aeb.x, sb.x + d1b.x)));
            ph[5] = (half_t)__expf(lrelu(fmaf(ea, aeb.y, sb.y + d1b.y)));
            ph[6] = (half_t)__expf(lrelu(fmaf(ea, aeb.z, sb.z + d1b.z)));
            ph[7] = (half_t)__expf(lrelu(fmaf(ea, aeb.w, sb.w + d1b.w)));
            pv = *(const int4*)ph;
        }
        sm_s[wv][lane] = s;
        *(int4*)&sm_p[wv][lane * 8] = pv;
        __builtin_amdgcn_wave_barrier();
        int cnt4 = (min(64, je - base) + 3) & ~3;   // pad edges have p=0
        for (int e = 0; e < cnt4; e += 4) {
            int s0  = sm_s[wv][e + 0];
            int s1_ = sm_s[wv][e + 1];
            int s2_ = sm_s[wv][e + 2];
            int s3  = sm_s[wv][e + 3];
            float p0  = (float)pp[(e + 0) * 8];
            float p1v = (float)pp[(e + 1) * 8];
            float p2v = (float)pp[(e + 2) * 8];
            float p3  = (float)pp[(e + 3) * 8];
            float h0  = ldbf(H1, ((uint_t)s0  << 7) + lb);
            float h1  = ldbf(H1, ((uint_t)s1_ << 7) + lb);
            float h2_ = ldbf(H1, ((uint_t)s2_ << 7) + lb);
            float h3  = ldbf(H1, ((uint_t)s3  << 7) + lb);
            den0 += p0 + p1v;
            den1 += p2v + p3;
            acc0 = fmaf(p0,  h0,  fmaf(p1v, h1, acc0));
            acc1 = fmaf(p2v, h2_, fmaf(p3,  h3, acc1));
        }
        __builtin_amdgcn_wave_barrier();
    }
    float den = den0 + den1;
    float acc = acc0 + acc1;
    float o = acc / (den + 1e-16f);
    float r = o > 0.f ? o : __expf(o) - 1.f;   // elu
    out1r[(size_t)w * C1 + lane] = f2bf(r);
}

// ---- K_gemm2 (MFMA): H2 = out1r @ W2 + s2/d2 dots ----
__global__ __launch_bounds__(256) void k_gemm2(
    const ushort_t* __restrict__ out1r, const ushort_t* __restrict__ W2p,
    const float* __restrict__ as2, const float* __restrict__ ad2,
    ushort_t* __restrict__ H2, float* __restrict__ s2, float* __restrict__ d2)
{
    int tile = (blockIdx.x * blockDim.x + threadIdx.x) >> 6;
    int lane = threadIdx.x & 63;
    if (tile >= N_NODES / 16) return;
    int quad = lane >> 4, lo = lane & 15;
    const ushort_t* arow = out1r + ((size_t)tile * 16 + lo) * C1 + quad * 8;
    short8 a0 = *(const short8*)arow;
    short8 a1 = *(const short8*)(arow + 32);
    f32x4 acc[3] = {{0,0,0,0},{0,0,0,0},{0,0,0,0}};
    #pragma unroll
    for (int nt = 0; nt < 3; ++nt) {
        short8 b0 = *(const short8*)&W2p[((nt * 2 + 0) * 64 + lane) * 8];
        short8 b1 = *(const short8*)&W2p[((nt * 2 + 1) * 64 + lane) * 8];
        acc[nt] = __builtin_amdgcn_mfma_f32_16x16x32_bf16(a0, b0, acc[nt], 0, 0, 0);
        acc[nt] = __builtin_amdgcn_mfma_f32_16x16x32_bf16(a1, b1, acc[nt], 0, 0, 0);
    }
    float ps0 = 0.f, ps1 = 0.f, ps2 = 0.f, ps3 = 0.f;
    float pd0 = 0.f, pd1 = 0.f, pd2 = 0.f, pd3 = 0.f;
    #pragma unroll
    for (int nt = 0; nt < 3; ++nt) {
        int cb = nt * 16 + lo;
        float a2 = cb < C2 ? as2[cb] : 0.f;
        float b2 = cb < C2 ? ad2[cb] : 0.f;
        float v0 = acc[nt][0], v1 = acc[nt][1], v2 = acc[nt][2], v3 = acc[nt][3];
        int nb = tile * 16 + quad * 4;
        H2[(size_t)(nb + 0) * C1 + cb] = f2bf(v0);
        H2[(size_t)(nb + 1) * C1 + cb] = f2bf(v1);
        H2[(size_t)(nb + 2) * C1 + cb] = f2bf(v2);
        H2[(size_t)(nb + 3) * C1 + cb] = f2bf(v3);
        ps0 = fmaf(v0, a2, ps0); ps1 = fmaf(v1, a2, ps1);
        ps2 = fmaf(v2, a2, ps2); ps3 = fmaf(v3, a2, ps3);
        pd0 = fmaf(v0, b2, pd0); pd1 = fmaf(v1, b2, pd1);
        pd2 = fmaf(v2, b2, pd2); pd3 = fmaf(v3, b2, pd3);
    }
    #pragma unroll
    for (int off = 1; off < 16; off <<= 1) {
        ps0 += __shfl_xor(ps0, off); ps1 += __shfl_xor(ps1, off);
        ps2 += __shfl_xor(ps2, off); ps3 += __shfl_xor(ps3, off);
        pd0 += __shfl_xor(pd0, off); pd1 += __shfl_xor(pd1, off);
        pd2 += __shfl_xor(pd2, off); pd3 += __shfl_xor(pd3, off);
    }
    if (lo == 0) {
        int nb = tile * 16 + quad * 4;
        s2[nb + 0] = ps0; s2[nb + 1] = ps1; s2[nb + 2] = ps2; s2[nb + 3] = ps3;
        d2[nb + 0] = pd0; d2[nb + 1] = pd1; d2[nb + 2] = pd2; d2[nb + 3] = pd3;
    }
}

// ---- K_node2 with FUSED logit2 + fused log_softmax epilogue ----
__global__ __launch_bounds__(256) void k_node2(
    const int* __restrict__ rowptr, const int2* __restrict__ edges,
    const float* __restrict__ s2, const float* __restrict__ d2,
    const float* __restrict__ ae2,
    const ushort_t* __restrict__ H2, float* __restrict__ out)
{
    __shared__ int2 sp[4][64];            // (src, p_float_bits) per wave
    int w = (blockIdx.x * blockDim.x + threadIdx.x) >> 6;
    int lane = threadIdx.x & 63;
    int wv = (threadIdx.x >> 6) & 3;
    if (w >= N_NODES) return;
    int c = lane < C2 ? lane : 0;
    int jb = rowptr[w], je = rowptr[w + 1];
    float d2v = d2[w];
    float aev = ae2[0];
    float den0 = 0.f, den1 = 0.f;
    float acc0 = 0.f, acc1 = 0.f;
    uint_t cb2 = (uint_t)c << 1;
    for (int base = jb; base < je; base += 64) {
        int idx = base + lane;
        int s = 0; float p = 0.f;
        if (idx < je) {
            int2 ed = edges[idx];
            s = ed.x;
            p = __expf(lrelu(s2[s] + d2v + __int_as_float(ed.y) * aev));
        }
        sp[wv][lane] = make_int2(s, __float_as_int(p));
        __builtin_amdgcn_wave_barrier();
        int cnt4 = (min(64, je - base) + 3) & ~3;   // pad edges have p=0
        for (int e = 0; e < cnt4; e += 4) {
            int2 e0 = sp[wv][e + 0];
            int2 e1 = sp[wv][e + 1];
            int2 e2 = sp[wv][e + 2];
            int2 e3 = sp[wv][e + 3];
            float h0  = ldbf(H2, ((uint_t)e0.x << 7) + cb2);
            float h1  = ldbf(H2, ((uint_t)e1.x << 7) + cb2);
            float h2_ = ldbf(H2, ((uint_t)e2.x << 7) + cb2);
            float h3  = ldbf(H2, ((uint_t)e3.x << 7) + cb2);
            float p0  = __int_as_float(e0.y);
            float p1v = __int_as_float(e1.y);
            float p2v = __int_as_float(e2.y);
            float p3  = __int_as_float(e3.y);
            den0 += p0 + p1v;
            den1 += p2v + p3;
            acc0 = fmaf(p0,  h0,  fmaf(p1v, h1, acc0));
            acc1 = fmaf(p2v, h2_, fmaf(p3,  h3, acc1));
        }
        __builtin_amdgcn_wave_barrier();
    }
    float den = den0 + den1;
    float acc = acc0 + acc1;
    float o = acc / (den + 1e-16f);
    float v = lane < C2 ? o : -INFINITY;
    float m = v;
    #pragma unroll
    for (int off = 32; off; off >>= 1) m = fmaxf(m, __shfl_xor(m, off));
    float p = lane < C2 ? __expf(v - m) : 0.f;
    #pragma unroll
    for (int off = 32; off; off >>= 1) p += __shfl_xor(p, off);
    float ls = __logf(p);
    if (lane < C2) out[(size_t)w * C2 + lane] = v - m - ls;
}

extern "C" void kernel_launch(void* const* d_in, const int* in_sizes, int n_in,
                              void* d_out, int out_size, void* d_ws, size_t ws_size,
                              hipStream_t stream)
{
    const float* x   = (const float*)d_in[0];
    const int*   ei  = (const int*)  d_in[1];
    const float* ea  = (const float*)d_in[2];
    const float* W1  = (const float*)d_in[3];
    const float* as1 = (const float*)d_in[4];
    const float* ad1 = (const float*)d_in[5];
    const float* ae1 = (const float*)d_in[6];
    const float* W2  = (const float*)d_in[7];
    const float* as2 = (const float*)d_in[8];
    const float* ad2 = (const float*)d_in[9];
    const float* ae2 = (const float*)d_in[10];
    float* out = (float*)d_out;

    // workspace layout (4-byte units):
    //   H1 [0,3.2M) dead after k_node1 -> reused as H2 (k_gemm2 writes)
    //   out1r region [3.2M,6.4M): CSR-build temps (Hblk/totB/baseB) live
    //     there first (dead after k_scatter2), then out1r (k_node1 writes)
    //   edges (final CSR int2) in [6.4M,9.6M)
    //   xb (bf16 x) in [9.6M,16.0M): dead after k_gemm1_mfma; coarse
    //     (int4 bucketed edges) aliases it, dead after k_scatter2
    //   rowptr needs 100,001 ints -> s2 starts 8 words later
    float*    ws     = (float*)d_ws;
    ushort_t* H1     = (ushort_t*)ws;                 // [0, 3.2M)  bf16
    ushort_t* H2     = (ushort_t*)ws;                 //   alias (after node1)
    ushort_t* out1r  = (ushort_t*)(ws + 3200000);     // [3.2M, 6.4M)
    int*      Hblk   = (int*)(ws + 3200000);          //   alias: 391*391 ints
    int*      totB   = (int*)(ws + 3360000);          //   alias: 391 ints
    int*      baseB  = (int*)(ws + 3361000);          //   alias: 392 ints
    int2*     edges  = (int2*)(ws + 6400000);         // [6.4M, 9.6M)
    ushort_t* xb     = (ushort_t*)(ws + 9600000);     // [9.6M, 16.0M) bf16 x
    int4*     coarse = (int4*)(ws + 9600000);         //   alias (after gemm1)
    float*    s1     = ws + 16000000;                 // [16.0M, 16.8M)
    float*    d1     = ws + 16800000;                 // [16.8M, 17.6M)
    int*      rowptr = (int*)(ws + 17600000);         // 100,001 ints
    float*    s2     = ws + 17700008;                 // 100,000
    float*    d2     = ws + 17800008;                 // 100,000
    ushort_t* W2p    = (ushort_t*)(ws + 17900008);    // 3072 bf16 (1536 w)
    ushort_t* W1p    = (ushort_t*)(ws + 17901544);    // 8192 bf16 (4096 w)

    k_prep      <<<XCAST_BLKS + WPREP_BLKS, 256, 0, stream>>>(x, xb, W1, W1p, W2, W2p);
    k_gemm1_mfma<<<(N_NODES / 16 + 3) / 4, 256, 0, stream>>>(xb, W1p, as1, ad1,
                                                             H1, s1, d1);
    // counting-sort CSR build (xb dead from here; coarse aliases it)
    k_hist1     <<<B1, 256, 0, stream>>>(ei, Hblk);
    k_colscan   <<<NBIN, 512, 0, stream>>>(Hblk, totB);
    k_basescan  <<<1, 512, 0, stream>>>(totB, baseB, rowptr);
    k_scatter1  <<<B1, 256, 0, stream>>>(ei, ea, Hblk, baseB, coarse);
    k_scatter2  <<<NBIN, 256, 0, stream>>>(coarse, baseB, edges, rowptr);
    // aggregation (logit fused into node kernels)
    k_node1     <<<(N_NODES + 3) / 4, 256, 0, stream>>>(rowptr, edges, s1, d1, ae1,
                                                        H1, out1r);
    k_gemm2     <<<(N_NODES / 16 + 3) / 4, 256, 0, stream>>>(out1r, W2p, as2, ad2,
                                                             H2, s2, d2);
    k_node2     <<<(N_NODES + 3) / 4, 256, 0, stream>>>(rowptr, edges, s2, d2, ae2,
                                                        H2, out);
}